// Round 16
// baseline (172.908 us; speedup 1.0000x reference)
//
#include <hip/hip_runtime.h>
#include <hip/hip_cooperative_groups.h>

namespace cg = cooperative_groups;

#define N_NODES 10000
#define N_EDGES 640000
#define D_FEAT 128
#define NGROUPS 8
#define NPG (N_NODES / NGROUPS)   // 1250
#define STRIDE 256                // padded CSR slots per node

// ---- ws layout (bytes) ----
#define WS_CURSORS 0                        // int[10000]
#define WS_CSR     40960                    // ushort[2,560,000] = 5.12 MB
#define WS_X16     (40960 + 5120000)        // _Float16[1,280,000] = 2.56 MB

typedef int          iv4 __attribute__((ext_vector_type(4)));
typedef unsigned int uv4 __attribute__((ext_vector_type(4)));
typedef float        fv8 __attribute__((ext_vector_type(8)));
typedef _Float16     hv8 __attribute__((ext_vector_type(8)));

#define CV(H) __builtin_convertvector((H), fv8)

#define ROWSUM8(A)                                                     \
    {                                                                  \
        int ii[8];                                                     \
        ii[0] = (A)[0] & 0xFFFF; ii[1] = (A)[0] >> 16;                 \
        ii[2] = (A)[1] & 0xFFFF; ii[3] = (A)[1] >> 16;                 \
        ii[4] = (A)[2] & 0xFFFF; ii[5] = (A)[2] >> 16;                 \
        ii[6] = (A)[3] & 0xFFFF; ii[7] = (A)[3] >> 16;                 \
        hv8 h[8];                                                      \
        _Pragma("unroll")                                              \
        for (int u = 0; u < 8; ++u)                                    \
            h[u] = *(const hv8*)(x16 + (size_t)ii[u] * D_FEAT + f);    \
        fv8 t0 = (CV(h[0]) + CV(h[1])) + (CV(h[2]) + CV(h[3]));        \
        fv8 t1 = (CV(h[4]) + CV(h[5])) + (CV(h[6]) + CV(h[7]));        \
        acc += t0 + t1;                                                \
    }

// Shared gather body: sum csr segment of `node`, normalize, one NT store.
__device__ __forceinline__ void gather_node(
    const _Float16* __restrict__ x16, const unsigned short* __restrict__ csr,
    const int* __restrict__ cursors, const float* __restrict__ deg,
    float* __restrict__ out, int node, int f) {
    const int count = cursors[node];
    int j = node * STRIDE;
    const int end = j + count;
    fv8 acc = (fv8)0.0f;
    if (j + 8 <= end) {
        uv4 a = *(const uv4*)(csr + j);
        for (; j + 16 <= end; j += 8) {
            uv4 n = *(const uv4*)(csr + j + 8);
            ROWSUM8(a)
            a = n;
        }
        ROWSUM8(a)
        j += 8;
    }
    for (; j < end; ++j) {
        hv8 h = *(const hv8*)(x16 + (size_t)csr[j] * D_FEAT + f);
        acc += CV(h);
    }
    const float inv = 1.0f / deg[node];
    fv8 rv = acc * inv;
    __builtin_nontemporal_store(rv, (fv8*)(&out[(size_t)node * D_FEAT + f]));
}

// ================= cooperative mega-kernel (256 blocks = 1/CU) =================
#define MEGA_BLOCKS 256
#define MEGA_THREADS 512
#define M_NCHUNKS 32
#define M_IV4 (N_EDGES / M_NCHUNKS / 4)     // 5000 int4 = 20000 edges/chunk
#define M_QCAP 4096                         // mean 2500, +34 sigma
#define CONV_V8 (N_NODES * D_FEAT / 8)      // 160000

__global__ __launch_bounds__(MEGA_THREADS) void mega_kernel(
    const float* __restrict__ x,
    _Float16* __restrict__ x16,
    const int* __restrict__ src,
    const int* __restrict__ dst,
    int* __restrict__ cursors,
    unsigned short* __restrict__ csr,
    const float* __restrict__ deg,
    float* __restrict__ out) {
    cg::grid_group grid = cg::this_grid();
    const int b = blockIdx.x;
    const int t = threadIdx.x;
    const int gid = b * MEGA_THREADS + t;

    // ---- P0: zero cursors + fp32->fp16 convert ----
    if (gid < N_NODES) cursors[gid] = 0;
    for (int i = gid; i < CONV_V8; i += MEGA_BLOCKS * MEGA_THREADS) {
        fv8 v = *(const fv8*)(x + (size_t)i * 8);
        *(hv8*)(x16 + (size_t)i * 8) = __builtin_convertvector(v, hv8);
    }
    grid.sync();

    // ---- P1: single-scan fill with LDS edge queue ----
    __shared__ int cnt[NPG];
    __shared__ int base[NPG];
    __shared__ int queue[M_QCAP];
    __shared__ int qn;
    {
        const int k = b & 7;            // group
        const int c = b >> 3;           // chunk 0..31
        const int lo = k * NPG;
        const int v0 = c * M_IV4;
        const int lane = t & 63;

        if (t == 0) qn = 0;
        for (int i = t; i < NPG; i += MEGA_THREADS) cnt[i] = 0;
        __syncthreads();

        for (int v = t; v < M_IV4; v += MEGA_THREADS) {
            iv4 d4 = ((const iv4*)dst)[v0 + v];
            iv4 s4 = ((const iv4*)src)[v0 + v];
            #pragma unroll
            for (int kk = 0; kk < 4; ++kk) {
                const int ln = d4[kk] - lo;
                const bool m = ((unsigned)ln < (unsigned)NPG);
                unsigned long long mask = __ballot(m);
                if (mask) {
                    const int lead = __ffsll(mask) - 1;
                    int qb = 0;
                    if (lane == lead) qb = atomicAdd(&qn, __popcll(mask));
                    qb = __shfl(qb, lead);
                    if (m) {
                        atomicAdd(&cnt[ln], 1);
                        const int my = __popcll(mask & ((1ull << lane) - 1));
                        queue[qb + my] = (ln << 14) | s4[kk];
                    }
                }
            }
        }
        __syncthreads();
        const int qtot = qn;

        for (int i = t; i < NPG; i += MEGA_THREADS) {
            int cc = cnt[i];
            int off = cc ? atomicAdd(&cursors[lo + i], cc) : 0;
            base[i] = (lo + i) * STRIDE + off;
            cnt[i] = 0;
        }
        __syncthreads();

        for (int i = t; i < qtot; i += MEGA_THREADS) {
            const int e = queue[i];
            const int ln = e >> 14;
            const int slot = base[ln] + atomicAdd(&cnt[ln], 1);
            csr[slot] = (unsigned short)(e & 0x3FFF);
        }
    }
    grid.sync();

    // ---- P2: gather. group k = b&7, r = b>>3 (0..31), 40 nodes per (k,r). ----
    const int g = t >> 4;               // 0..31
    const int lane16 = t & 15;
    const int r = b >> 3;
    const int f = lane16 << 3;
    const _Float16* __restrict__ xx = x16;
    {
        const _Float16* x16_ = xx;  (void)x16_;
    }
    for (int gg = g; gg < 40; gg += 32) {
        const int nig = r * 40 + gg;
        if (nig < NPG) {
            const int node = (b & 7) * NPG + nig;
            gather_node(x16, csr, cursors, deg, out, node, f);
        }
    }
}

// ================= fallback path (r14-proven, 3 dispatches) =================
#define FB_THREADS 512
#define FB_FILL_BLOCKS 512
#define FB_IV4 (N_EDGES / 64 / 4)           // 2500
#define FB_QCAP 2048
#define FB_CONV_BLOCKS ((CONV_V8 + FB_THREADS - 1) / FB_THREADS)  // 313
#define FB_HYBRID_BLOCKS (FB_FILL_BLOCKS + FB_CONV_BLOCKS)

__global__ __launch_bounds__(FB_THREADS) void hybrid_kernel(
    const float* __restrict__ x,
    _Float16* __restrict__ x16,
    const int* __restrict__ src,
    const int* __restrict__ dst,
    int* __restrict__ cursors,
    unsigned short* __restrict__ csr) {
    const int b = blockIdx.x;
    const int t = threadIdx.x;

    if (b >= FB_FILL_BLOCKS) {
        const int i = (b - FB_FILL_BLOCKS) * FB_THREADS + t;
        if (i < CONV_V8) {
            fv8 v = *(const fv8*)(x + (size_t)i * 8);
            *(hv8*)(x16 + (size_t)i * 8) = __builtin_convertvector(v, hv8);
        }
        return;
    }

    __shared__ int cnt[NPG];
    __shared__ int base[NPG];
    __shared__ int queue[FB_QCAP];
    __shared__ int qn;
    const int k = b & 7;
    const int c = b >> 3;
    const int lo = k * NPG;
    const int v0 = c * FB_IV4;
    const int lane = t & 63;

    if (t == 0) qn = 0;
    for (int i = t; i < NPG; i += FB_THREADS) cnt[i] = 0;
    __syncthreads();

    for (int v = t; v < FB_IV4; v += FB_THREADS) {
        iv4 d4 = ((const iv4*)dst)[v0 + v];
        iv4 s4 = ((const iv4*)src)[v0 + v];
        #pragma unroll
        for (int kk = 0; kk < 4; ++kk) {
            const int ln = d4[kk] - lo;
            const bool m = ((unsigned)ln < (unsigned)NPG);
            unsigned long long mask = __ballot(m);
            if (mask) {
                const int lead = __ffsll(mask) - 1;
                int qb = 0;
                if (lane == lead) qb = atomicAdd(&qn, __popcll(mask));
                qb = __shfl(qb, lead);
                if (m) {
                    atomicAdd(&cnt[ln], 1);
                    const int my = __popcll(mask & ((1ull << lane) - 1));
                    queue[qb + my] = (ln << 14) | s4[kk];
                }
            }
        }
    }
    __syncthreads();
    const int qtot = qn;

    for (int i = t; i < NPG; i += FB_THREADS) {
        int cc = cnt[i];
        int off = cc ? atomicAdd(&cursors[lo + i], cc) : 0;
        base[i] = (lo + i) * STRIDE + off;
        cnt[i] = 0;
    }
    __syncthreads();

    for (int i = t; i < qtot; i += FB_THREADS) {
        const int e = queue[i];
        const int ln = e >> 14;
        const int slot = base[ln] + atomicAdd(&cnt[ln], 1);
        csr[slot] = (unsigned short)(e & 0x3FFF);
    }
}

#define GBPG 79
#define GATHER_BLOCKS (GBPG * NGROUPS)      // 632
__global__ __launch_bounds__(256) void gather_kernel(
    const _Float16* __restrict__ x16,
    const int* __restrict__ cursors,
    const unsigned short* __restrict__ csr,
    const float* __restrict__ deg,
    float* __restrict__ out) {
    const int b = blockIdx.x;
    const int r = b >> 3;
    const int g = threadIdx.x >> 4;
    const int lane16 = threadIdx.x & 15;
    const int nig = r * 16 + g;
    if (nig >= NPG) return;
    const int node = (b & 7) * NPG + nig;
    gather_node(x16, csr, cursors, deg, out, node, lane16 << 3);
}

extern "C" void kernel_launch(void* const* d_in, const int* in_sizes, int n_in,
                              void* d_out, int out_size, void* d_ws, size_t ws_size,
                              hipStream_t stream) {
    const float* x   = (const float*)d_in[0];
    const int*   ei  = (const int*)d_in[1];   // [2, N_EDGES] flat: src row, dst row
    const float* deg = (const float*)d_in[2];
    float* out = (float*)d_out;

    const int* src = ei;
    const int* dst = ei + N_EDGES;

    char* ws = (char*)d_ws;
    int*            cursors = (int*)(ws + WS_CURSORS);
    unsigned short* csr     = (unsigned short*)(ws + WS_CSR);
    _Float16*       x16     = (_Float16*)(ws + WS_X16);

    void* args[] = {(void*)&x, (void*)&x16, (void*)&src, (void*)&dst,
                    (void*)&cursors, (void*)&csr, (void*)&deg, (void*)&out};
    hipError_t e = hipLaunchCooperativeKernel((void*)mega_kernel, dim3(MEGA_BLOCKS),
                                              dim3(MEGA_THREADS), args, 0, stream);
    if (e != hipSuccess) {
        // Deterministic fallback: proven r14 3-dispatch path.
        hipMemsetAsync(cursors, 0, N_NODES * sizeof(int), stream);
        hybrid_kernel<<<FB_HYBRID_BLOCKS, FB_THREADS, 0, stream>>>(
            x, x16, src, dst, cursors, csr);
        gather_kernel<<<GATHER_BLOCKS, 256, 0, stream>>>(x16, cursors, csr, deg, out);
    }
}

// Round 17
// 93.655 us; speedup vs baseline: 1.8462x; 1.8462x over previous
//
#include <hip/hip_runtime.h>

#define N_NODES 10000
#define N_EDGES 640000
#define D_FEAT 128
#define NGROUPS 8
#define NPG (N_NODES / NGROUPS)   // 1250
#define STRIDE 256                // padded CSR slots per node (max deg ~112 << 256)
#define QCAP 2048                 // LDS queue capacity (mean 1250, sigma 33)

// ---- ws layout (bytes) ----
#define WS_CURSORS 0                        // int[10000]
#define WS_CSR     40960                    // ushort[2,560,000] = 5.12 MB
#define WS_X16     (40960 + 5120000)        // _Float16[1,280,000] = 2.56 MB

typedef int          iv4 __attribute__((ext_vector_type(4)));
typedef unsigned int uv4 __attribute__((ext_vector_type(4)));
typedef float        fv8 __attribute__((ext_vector_type(8)));
typedef _Float16     hv8 __attribute__((ext_vector_type(8)));

// Hybrid kernel: blocks 0..511 build the CSR (single-scan fill with LDS edge
// queue); remaining blocks run the fp32->fp16 convert concurrently.
#define FILL_THREADS 512
#define FILL_BLOCKS 512
#define NCHUNKS_F 64
#define IV4_PER_CHUNK (N_EDGES / NCHUNKS_F / 4)        // 2500
#define CONV_V8 (N_NODES * D_FEAT / 8)                 // 160000 fv8 elements
#define CONV_BLOCKS ((CONV_V8 + FILL_THREADS - 1) / FILL_THREADS)  // 313
#define HYBRID_BLOCKS (FILL_BLOCKS + CONV_BLOCKS)

__global__ __launch_bounds__(FILL_THREADS) void hybrid_kernel(
    const float* __restrict__ x,
    _Float16* __restrict__ x16,
    const int* __restrict__ src,
    const int* __restrict__ dst,
    int* __restrict__ cursors,
    unsigned short* __restrict__ csr) {
    const int b = blockIdx.x;
    const int t = threadIdx.x;

    if (b >= FILL_BLOCKS) {
        // ---- convert role ----
        const int i = (b - FILL_BLOCKS) * FILL_THREADS + t;
        if (i < CONV_V8) {
            fv8 v = *(const fv8*)(x + (size_t)i * 8);
            *(hv8*)(x16 + (size_t)i * 8) = __builtin_convertvector(v, hv8);
        }
        return;
    }

    // ---- fill role: single-scan fill with LDS edge queue ----
    __shared__ int cnt[NPG];
    __shared__ int base[NPG];
    __shared__ int queue[QCAP];
    __shared__ int qn;
    const int k = b & 7;            // group -> csr slice (XCD-local if %8 maps)
    const int c = b >> 3;           // chunk 0..63
    const int lo = k * NPG;
    const int v0 = c * IV4_PER_CHUNK;
    const int lane = t & 63;

    if (t == 0) qn = 0;
    for (int i = t; i < NPG; i += FILL_THREADS) cnt[i] = 0;
    __syncthreads();

    // Pass A: single scan of dst+src; histogram + ballot-aggregated queue append.
    for (int v = t; v < IV4_PER_CHUNK; v += FILL_THREADS) {
        iv4 d4 = ((const iv4*)dst)[v0 + v];
        iv4 s4 = ((const iv4*)src)[v0 + v];
        #pragma unroll
        for (int kk = 0; kk < 4; ++kk) {
            const int ln = d4[kk] - lo;
            const bool m = ((unsigned)ln < (unsigned)NPG);
            unsigned long long mask = __ballot(m);
            if (mask) {
                const int lead = __ffsll(mask) - 1;
                int qb = 0;
                if (lane == lead) qb = atomicAdd(&qn, __popcll(mask));
                qb = __shfl(qb, lead);
                if (m) {
                    atomicAdd(&cnt[ln], 1);
                    const int my = __popcll(mask & ((1ull << lane) - 1));
                    queue[qb + my] = (ln << 14) | s4[kk];
                }
            }
        }
    }
    __syncthreads();

    const int qtot = qn;

    // Bulk reservation: one global atomic per touched node.
    for (int i = t; i < NPG; i += FILL_THREADS) {
        int cc = cnt[i];
        int off = cc ? atomicAdd(&cursors[lo + i], cc) : 0;
        base[i] = (lo + i) * STRIDE + off;
        cnt[i] = 0;                 // reuse as local cursor
    }
    __syncthreads();

    // Pass B: drain the LDS queue (no global re-reads).
    for (int i = t; i < qtot; i += FILL_THREADS) {
        const int e = queue[i];
        const int ln = e >> 14;
        const int slot = base[ln] + atomicAdd(&cnt[ln], 1);
        csr[slot] = (unsigned short)(e & 0x3FFF);
    }
}

// Gather on fp16 rows with ushort indices: 16 lanes/node, 16 nodes per
// 256-thread block; %8 grouping matches fill so csr + x16 stay XCD-L2-hot.
#define GBPG 79                               // ceil(1250/16)
#define GATHER_BLOCKS (GBPG * NGROUPS)        // 632

#define CV(H) __builtin_convertvector((H), fv8)

#define ROWSUM16(A0, A1)                                                     \
    {                                                                        \
        int ia[8], ib[8];                                                    \
        ia[0] = (A0)[0] & 0xFFFF; ia[1] = (A0)[0] >> 16;                     \
        ia[2] = (A0)[1] & 0xFFFF; ia[3] = (A0)[1] >> 16;                     \
        ia[4] = (A0)[2] & 0xFFFF; ia[5] = (A0)[2] >> 16;                     \
        ia[6] = (A0)[3] & 0xFFFF; ia[7] = (A0)[3] >> 16;                     \
        ib[0] = (A1)[0] & 0xFFFF; ib[1] = (A1)[0] >> 16;                     \
        ib[2] = (A1)[1] & 0xFFFF; ib[3] = (A1)[1] >> 16;                     \
        ib[4] = (A1)[2] & 0xFFFF; ib[5] = (A1)[2] >> 16;                     \
        ib[6] = (A1)[3] & 0xFFFF; ib[7] = (A1)[3] >> 16;                     \
        hv8 h[16];                                                           \
        _Pragma("unroll")                                                    \
        for (int u = 0; u < 8; ++u) {                                        \
            h[u]     = *(const hv8*)(x16 + (size_t)ia[u] * D_FEAT + f);      \
            h[8 + u] = *(const hv8*)(x16 + (size_t)ib[u] * D_FEAT + f);      \
        }                                                                    \
        fv8 t0 = (CV(h[0]) + CV(h[1])) + (CV(h[2]) + CV(h[3]));              \
        fv8 t1 = (CV(h[4]) + CV(h[5])) + (CV(h[6]) + CV(h[7]));              \
        fv8 t2 = (CV(h[8]) + CV(h[9])) + (CV(h[10]) + CV(h[11]));            \
        fv8 t3 = (CV(h[12]) + CV(h[13])) + (CV(h[14]) + CV(h[15]));          \
        acc += (t0 + t1) + (t2 + t3);                                        \
    }

__global__ __launch_bounds__(256) void gather_kernel(
    const _Float16* __restrict__ x16,
    const int* __restrict__ cursors,   // post-fill: exact per-node counts
    const unsigned short* __restrict__ csr,
    const float* __restrict__ deg,
    float* __restrict__ out) {
    const int b = blockIdx.x;
    const int k = b & 7;
    const int r = b >> 3;
    const int g = threadIdx.x >> 4;     // node-in-block 0..15
    const int lane = threadIdx.x & 15;
    const int nig = r * 16 + g;
    if (nig >= NPG) return;
    const int node = k * NPG + nig;
    const int f = lane << 3;            // 8 features per lane

    const int count = cursors[node];
    int j = node * STRIDE;              // ushort units
    const int end = j + count;

    fv8 acc = (fv8)0.0f;

    if (j + 16 <= end) {
        uv4 a0 = *(const uv4*)(csr + j);
        uv4 a1 = *(const uv4*)(csr + j + 8);
        for (; j + 32 <= end; j += 16) {
            uv4 n0 = *(const uv4*)(csr + j + 16);
            uv4 n1 = *(const uv4*)(csr + j + 24);
            ROWSUM16(a0, a1)
            a0 = n0; a1 = n1;
        }
        ROWSUM16(a0, a1)
        j += 16;
    }
    for (; j < end; ++j) {
        hv8 h = *(const hv8*)(x16 + (size_t)csr[j] * D_FEAT + f);
        acc += CV(h);
    }

    const float inv = 1.0f / deg[node];
    fv8 rv = acc * inv;
    __builtin_nontemporal_store(rv, (fv8*)(&out[(size_t)node * D_FEAT + f]));
}

extern "C" void kernel_launch(void* const* d_in, const int* in_sizes, int n_in,
                              void* d_out, int out_size, void* d_ws, size_t ws_size,
                              hipStream_t stream) {
    const float* x   = (const float*)d_in[0];
    const int*   ei  = (const int*)d_in[1];   // [2, N_EDGES] flat: src row, dst row
    const float* deg = (const float*)d_in[2];
    float* out = (float*)d_out;

    const int* src = ei;
    const int* dst = ei + N_EDGES;

    char* ws = (char*)d_ws;
    int*            cursors = (int*)(ws + WS_CURSORS);
    unsigned short* csr     = (unsigned short*)(ws + WS_CSR);
    _Float16*       x16     = (_Float16*)(ws + WS_X16);

    hipMemsetAsync(cursors, 0, N_NODES * sizeof(int), stream);
    hybrid_kernel<<<HYBRID_BLOCKS, FILL_THREADS, 0, stream>>>(x, x16, src, dst, cursors, csr);
    gather_kernel<<<GATHER_BLOCKS, 256, 0, stream>>>(x16, cursors, csr, deg, out);
}